// Round 1
// baseline (434.714 us; speedup 1.0000x reference)
//
#include <hip/hip_runtime.h>
#include <math.h>

#define Wd 160
#define Hd 128
#define Cd 32
#define Dd 64
#define HWd (Hd * Wd)
#define PV_OFF (3 * HWd)
#define VW_OFF (67 * HWd)

// ws float offsets
#define WS_ROT 0      // 4 views * 12 floats (rot row-major 9, trans 3)
#define WS_A0 64
#define WS_B0 80
#define WS_W1 96
#define WS_B1 224
#define WS_W2 232
#define WS_BIAS2 240
#define WS_CW0 241
#define WS_CB0 249
#define WS_CW1 257
#define WS_CB1 265
#define WS_TOTAL 272

__global__ void setup_kernel(const float* __restrict__ pm,
                             const float* __restrict__ pw_w0, const float* __restrict__ pw_g0,
                             const float* __restrict__ pw_b0, const float* __restrict__ pw_w1,
                             const float* __restrict__ pw_g1, const float* __restrict__ pw_b1,
                             const float* __restrict__ pw_w2, const float* __restrict__ pw_bias2,
                             const float* __restrict__ cr_w0, const float* __restrict__ cr_b0,
                             const float* __restrict__ cr_w1, const float* __restrict__ cr_b1,
                             float* __restrict__ wsf)
{
    if (blockIdx.x != 0 || threadIdx.x != 0) return;

    // fuse: F = E; F[:3,:4] = K[:3,:3] @ E[:3,:4]
    double F[5][16];
    for (int v = 0; v < 5; ++v) {
        const float* E = pm + v * 32;       // [v][0][4][4]
        const float* K = pm + v * 32 + 16;  // [v][1][4][4]
        double f[16];
        for (int i = 0; i < 16; ++i) f[i] = (double)E[i];
        for (int i = 0; i < 3; ++i)
            for (int j = 0; j < 4; ++j) {
                double s = 0.0;
                for (int k = 0; k < 3; ++k) s += (double)K[i * 4 + k] * (double)E[k * 4 + j];
                f[i * 4 + j] = s;
            }
        for (int i = 0; i < 16; ++i) F[v][i] = f[i];
    }

    // invert F[0] (Gauss-Jordan with partial pivoting)
    double A[4][8];
    for (int i = 0; i < 4; ++i)
        for (int j = 0; j < 4; ++j) { A[i][j] = F[0][i * 4 + j]; A[i][j + 4] = (i == j) ? 1.0 : 0.0; }
    for (int col = 0; col < 4; ++col) {
        int piv = col; double best = fabs(A[col][col]);
        for (int r = col + 1; r < 4; ++r) { double a = fabs(A[r][col]); if (a > best) { best = a; piv = r; } }
        if (piv != col)
            for (int j = 0; j < 8; ++j) { double t = A[col][j]; A[col][j] = A[piv][j]; A[piv][j] = t; }
        double inv = 1.0 / A[col][col];
        for (int j = 0; j < 8; ++j) A[col][j] *= inv;
        for (int r = 0; r < 4; ++r)
            if (r != col) {
                double m = A[r][col];
                for (int j = 0; j < 8; ++j) A[r][j] -= m * A[col][j];
            }
    }
    double inv0[16];
    for (int i = 0; i < 4; ++i)
        for (int j = 0; j < 4; ++j) inv0[i * 4 + j] = A[i][j + 4];

    // per source view: P = F[v] @ inv0; store rot (9) + trans (3)
    for (int v = 1; v < 5; ++v) {
        double P[16];
        for (int i = 0; i < 4; ++i)
            for (int j = 0; j < 4; ++j) {
                double s = 0.0;
                for (int k = 0; k < 4; ++k) s += F[v][i * 4 + k] * inv0[k * 4 + j];
                P[i * 4 + j] = s;
            }
        float* o = wsf + WS_ROT + (v - 1) * 12;
        o[0] = (float)P[0];  o[1] = (float)P[1];  o[2] = (float)P[2];
        o[3] = (float)P[4];  o[4] = (float)P[5];  o[5] = (float)P[6];
        o[6] = (float)P[8];  o[7] = (float)P[9];  o[8] = (float)P[10];
        o[9] = (float)P[3];  o[10] = (float)P[7]; o[11] = (float)P[11];
    }

    // fold BN scale (g * rsqrt(1+eps)) into conv weights
    const float rs = rsqrtf(1.0f + 1e-5f);
    for (int j = 0; j < 16; ++j) {
        wsf[WS_A0 + j] = pw_w0[j] * pw_g0[j] * rs;
        wsf[WS_B0 + j] = pw_b0[j];
    }
    for (int k = 0; k < 8; ++k) {
        float sk = pw_g1[k] * rs;
        for (int j = 0; j < 16; ++j) wsf[WS_W1 + k * 16 + j] = pw_w1[k * 16 + j] * sk;
        wsf[WS_B1 + k] = pw_b1[k];
        wsf[WS_W2 + k] = pw_w2[k];
    }
    wsf[WS_BIAS2] = pw_bias2[0];
    for (int j = 0; j < 8; ++j) {
        wsf[WS_CW0 + j] = cr_w0[j];
        wsf[WS_CB0 + j] = cr_b0[j];
        wsf[WS_CW1 + j] = cr_w1[j];
    }
    wsf[WS_CB1] = cr_b1[0];
}

__global__ __launch_bounds__(256) void depthnet_main(
    const float* __restrict__ features,
    const float* __restrict__ depth_values,
    const float* __restrict__ wsf,
    float* __restrict__ out)
{
    __shared__ float sm[WS_TOTAL];
    const int tid = threadIdx.x;
    for (int i = tid; i < WS_TOTAL; i += 256) sm[i] = wsf[i];
    __syncthreads();

    const int pix = (blockIdx.x * 256 + tid) >> 6;  // one wave per pixel
    const int lane = tid & 63;                      // lane = depth index
    const float xf = (float)(pix % Wd);
    const float yf = (float)(pix / Wd);

    // reference features for this pixel (wave-uniform)
    float refc[Cd];
#pragma unroll
    for (int c = 0; c < Cd; ++c) refc[c] = features[c * HWd + pix];

    const float dep = depth_values[lane * HWd + pix];

    float sim_sum = 0.f;
    float w_sum = 1e-5f;

    for (int v = 0; v < 4; ++v) {
        const float* __restrict__ src = features + (v + 1) * Cd * HWd;
        const float* m = &sm[WS_ROT + v * 12];
        const float rX = m[0] * xf + m[1] * yf + m[2];
        const float rY = m[3] * xf + m[4] * yf + m[5];
        const float rZ = m[6] * xf + m[7] * yf + m[8];
        const float X = rX * dep + m[9];
        const float Y = rY * dep + m[10];
        const float Z = rZ * dep + m[11];
        const float pxf = X / Z;
        const float pyf = Y / Z;
        const float fx0 = floorf(pxf), fy0 = floorf(pyf);
        const float wx1 = pxf - fx0, wy1 = pyf - fy0;
        const float wx0 = 1.f - wx1, wy0 = 1.f - wy1;
        const float fx1 = fx0 + 1.f, fy1 = fy0 + 1.f;
        const float bx0 = (fx0 >= 0.f && fx0 <= (float)(Wd - 1)) ? 1.f : 0.f;
        const float bx1 = (fx1 >= 0.f && fx1 <= (float)(Wd - 1)) ? 1.f : 0.f;
        const float by0 = (fy0 >= 0.f && fy0 <= (float)(Hd - 1)) ? 1.f : 0.f;
        const float by1 = (fy1 >= 0.f && fy1 <= (float)(Hd - 1)) ? 1.f : 0.f;
        const float w00 = wx0 * wy0 * bx0 * by0;
        const float w01 = wx1 * wy0 * bx1 * by0;
        const float w10 = wx0 * wy1 * bx0 * by1;
        const float w11 = wx1 * wy1 * bx1 * by1;
        const int ix0 = (int)fminf(fmaxf(fx0, 0.f), (float)(Wd - 1));
        const int ix1 = (int)fminf(fmaxf(fx1, 0.f), (float)(Wd - 1));
        const int iy0 = (int)fminf(fmaxf(fy0, 0.f), (float)(Hd - 1));
        const int iy1 = (int)fminf(fmaxf(fy1, 0.f), (float)(Hd - 1));
        const int i00 = iy0 * Wd + ix0;
        const int i01 = iy0 * Wd + ix1;
        const int i10 = iy1 * Wd + ix0;
        const int i11 = iy1 * Wd + ix1;

        float acc = 0.f;
#pragma unroll
        for (int c = 0; c < Cd; ++c) {
            const float* p = src + c * HWd;
            const float bil = p[i00] * w00 + p[i01] * w01 + p[i10] * w10 + p[i11] * w11;
            acc += bil * refc[c];
        }
        const float sim = acc * (1.f / 32.f);

        // pixelwise net: 1 -> 16 -> 8 -> 1 (BN folded)
        float x0v[16];
#pragma unroll
        for (int j = 0; j < 16; ++j)
            x0v[j] = fmaxf(sm[WS_A0 + j] * sim + sm[WS_B0 + j], 0.f);
        float yv = sm[WS_BIAS2];
#pragma unroll
        for (int k = 0; k < 8; ++k) {
            float d0 = 0.f;
#pragma unroll
            for (int j = 0; j < 16; ++j) d0 += sm[WS_W1 + k * 16 + j] * x0v[j];
            const float x1 = fmaxf(d0 + sm[WS_B1 + k], 0.f);
            yv += sm[WS_W2 + k] * x1;
        }
        // vw = sigmoid(max_d yv) (sigmoid monotonic)
        float ymax = yv;
#pragma unroll
        for (int o = 32; o >= 1; o >>= 1) ymax = fmaxf(ymax, __shfl_xor(ymax, o, 64));
        const float vw = 1.f / (1.f + expf(-ymax));
        sim_sum += sim * vw;
        w_sum += vw;
        if (lane == 0) out[VW_OFF + v * HWd + pix] = vw;
    }

    const float simil = sim_sum / w_sum;

    // argmax similarity over depth (first index on ties) -> similarity_depth
    float bv = simil; int bi = lane;
#pragma unroll
    for (int o = 32; o >= 1; o >>= 1) {
        const float ov = __shfl_xor(bv, o, 64);
        const int oi = __shfl_xor(bi, o, 64);
        if (ov > bv || (ov == bv && oi < bi)) { bv = ov; bi = oi; }
    }
    const float sim_depth = __shfl(dep, bi, 64);

    // cr net: 1 -> 8 -> 1
    float y2 = sm[WS_CB1];
#pragma unroll
    for (int j = 0; j < 8; ++j) {
        const float h = fmaxf(sm[WS_CW0 + j] * simil + sm[WS_CB0 + j], 0.f);
        y2 += sm[WS_CW1 + j] * h;
    }
    // softmax over depth lanes
    float m2 = y2;
#pragma unroll
    for (int o = 32; o >= 1; o >>= 1) m2 = fmaxf(m2, __shfl_xor(m2, o, 64));
    const float e = expf(y2 - m2);
    float s = e;
#pragma unroll
    for (int o = 32; o >= 1; o >>= 1) s += __shfl_xor(s, o, 64);
    const float prob = e / s;
    out[PV_OFF + lane * HWd + pix] = prob;

    // argmax of y2 (== argmax of prob) -> depth WTA; conf = max prob = 1/s
    float bv2 = y2; int bi2 = lane;
#pragma unroll
    for (int o = 32; o >= 1; o >>= 1) {
        const float ov = __shfl_xor(bv2, o, 64);
        const int oi = __shfl_xor(bi2, o, 64);
        if (ov > bv2 || (ov == bv2 && oi < bi2)) { bv2 = ov; bi2 = oi; }
    }
    const float depth_o = __shfl(dep, bi2, 64);
    const float conf = 1.f / s;

    if (lane == 0) {
        out[pix] = depth_o;
        out[HWd + pix] = sim_depth;
        out[2 * HWd + pix] = conf;
    }
}

extern "C" void kernel_launch(void* const* d_in, const int* in_sizes, int n_in,
                              void* d_out, int out_size, void* d_ws, size_t ws_size,
                              hipStream_t stream)
{
    const float* features     = (const float*)d_in[0];
    const float* pm           = (const float*)d_in[1];
    const float* depth_values = (const float*)d_in[2];
    const float* pw_w0   = (const float*)d_in[4];
    const float* pw_g0   = (const float*)d_in[5];
    const float* pw_b0   = (const float*)d_in[6];
    const float* pw_w1   = (const float*)d_in[7];
    const float* pw_g1   = (const float*)d_in[8];
    const float* pw_b1   = (const float*)d_in[9];
    const float* pw_w2   = (const float*)d_in[10];
    const float* pw_bias2= (const float*)d_in[11];
    const float* cr_w0   = (const float*)d_in[12];
    const float* cr_b0   = (const float*)d_in[13];
    const float* cr_w1   = (const float*)d_in[14];
    const float* cr_b1   = (const float*)d_in[15];
    float* wsf = (float*)d_ws;
    float* out = (float*)d_out;

    hipLaunchKernelGGL(setup_kernel, dim3(1), dim3(64), 0, stream,
                       pm, pw_w0, pw_g0, pw_b0, pw_w1, pw_g1, pw_b1, pw_w2, pw_bias2,
                       cr_w0, cr_b0, cr_w1, cr_b1, wsf);

    hipLaunchKernelGGL(depthnet_main, dim3(HWd / 4), dim3(256), 0, stream,
                       features, depth_values, wsf, out);
}